// Round 10
// baseline (55.373 us; speedup 1.0000x reference)
//
#include <hip/hip_runtime.h>

#define HID   64
#define NHD   8
#define IT    8           // i's per block (halved vs r9 -> 1024 blocks, 4/CU)
#define IGRP  4           // i's per store burst
#define WAVES 8
#define JTW   32          // j's per wave (2 MFMA tiles of 16)
#define JT    (WAVES*JTW) // 256 j's per block

typedef _Float16 f16x8 __attribute__((ext_vector_type(8)));
typedef float    f32x4 __attribute__((ext_vector_type(4)));

// out[b,k,i,j] = sum_h relu( (u_j[h]+b1[h]) - u_i[h] ) * W2[h,k] + b2[k]
// r5/r9 fp16 MFMA pipeline (validated). r8 diag: write path sustains 5.6 TB/s
// with this exact store pattern when enough stores are outstanding; r9 at
// 16 waves/CU (2 blocks/CU, occupancy ~24%) ran at half that. This round:
// IT 16->8 doubles the grid to 1024 blocks = 4 blocks/CU = 32 waves/CU
// (VGPR 56 <= 64, LDS 2KB -> fits), doubling the outstanding-store pool.
__global__ __launch_bounds__(WAVES * 64, 8) void relposenc_occ(
    const float* __restrict__ xyz, const float* __restrict__ W1,
    const float* __restrict__ b1,  const float* __restrict__ W2,
    const float* __restrict__ b2,  float* __restrict__ out, int N) {

  __shared__ float    sW1b1[4][HID];
  __shared__ _Float16 sU[IT][HID];

  const int tid  = threadIdx.x;
  const int wave = tid >> 6;
  const int lane = tid & 63;
  const int col  = lane & 15;
  const int hgrp = lane >> 4;
  const int b    = blockIdx.z;
  const int i0   = blockIdx.y * IT;
  const int j0   = blockIdx.x * JT + wave * JTW;

  const float* xb = xyz + (size_t)b * 3 * N;

  if (tid < 4 * HID) {
    int r = tid >> 6, h = tid & 63;
    sW1b1[r][h] = (r < 3) ? W1[r * HID + h] : b1[h];
  }
  if (tid < IT * HID) {
    int ii = tid >> 6, h = tid & 63;
    int i  = i0 + ii;
    float u = fmaf(xb[i], W1[h],
              fmaf(xb[N + i], W1[HID + h],
                   xb[2 * N + i] * W1[2 * HID + h]));
    sU[ii][h] = (_Float16)u;
  }

  f16x8 aLo[2], aHi[2];
  #pragma unroll
  for (int kb = 0; kb < 2; ++kb)
    #pragma unroll
    for (int e = 0; e < 8; ++e) {
      int h = kb * 32 + hgrp * 8 + e;
      aLo[kb][e] = (_Float16)((col < NHD)  ? W2[h * NHD + col]       : 0.f);
      aHi[kb][e] = (_Float16)((col >= NHD) ? W2[h * NHD + (col - 8)] : 0.f);
    }
  float b2v[4];
  #pragma unroll
  for (int r = 0; r < 4; ++r) b2v[r] = b2[((hgrp & 1) << 2) + r];

  __syncthreads();

  f16x8 aj[2][2];
  #pragma unroll
  for (int t = 0; t < 2; ++t) {
    int j = j0 + t * 16 + col;
    float x0 = xb[j], x1 = xb[N + j], x2 = xb[2 * N + j];
    #pragma unroll
    for (int kb = 0; kb < 2; ++kb)
      #pragma unroll
      for (int e = 0; e < 8; ++e) {
        int h = kb * 32 + hgrp * 8 + e;
        float v = fmaf(x0, sW1b1[0][h],
                  fmaf(x1, sW1b1[1][h],
                  fmaf(x2, sW1b1[2][h], sW1b1[3][h])));
        aj[t][kb][e] = (_Float16)v;
      }
  }

  const size_t jj = (size_t)j0 + col + ((size_t)(lane >> 5) << 4);
  const int kbase = (hgrp & 1) << 2;
  const size_t baseOff = ((size_t)(b * NHD + kbase) * N + i0) * N + jj;
  const size_t plane = (size_t)N * N;

  const f16x8 z = {0, 0, 0, 0, 0, 0, 0, 0};

  for (int ig = 0; ig < IT; ig += IGRP) {
    f32x4 vals[IGRP];

    #pragma unroll
    for (int q = 0; q < IGRP; ++q) {
      f16x8 u0 = *(const f16x8*)&sU[ig + q][hgrp * 8];
      f16x8 u1 = *(const f16x8*)&sU[ig + q][32 + hgrp * 8];

      f16x8 d00 = __builtin_elementwise_max(aj[0][0] - u0, z);
      f16x8 d01 = __builtin_elementwise_max(aj[0][1] - u1, z);
      f16x8 d10 = __builtin_elementwise_max(aj[1][0] - u0, z);
      f16x8 d11 = __builtin_elementwise_max(aj[1][1] - u1, z);

      f32x4 cA = {b2v[0], b2v[1], b2v[2], b2v[3]};
      f32x4 cB = {0.f, 0.f, 0.f, 0.f};
      cA = __builtin_amdgcn_mfma_f32_16x16x32_f16(aLo[0], d00, cA, 0, 0, 0);
      cA = __builtin_amdgcn_mfma_f32_16x16x32_f16(aLo[1], d01, cA, 0, 0, 0);
      cB = __builtin_amdgcn_mfma_f32_16x16x32_f16(aHi[0], d10, cB, 0, 0, 0);
      cB = __builtin_amdgcn_mfma_f32_16x16x32_f16(aHi[1], d11, cB, 0, 0, 0);
      vals[q] = cA + cB;
    }

    #pragma unroll
    for (int r = 0; r < 4; ++r) {
      const size_t po = baseOff + (size_t)r * plane + (size_t)ig * N;
      #pragma unroll
      for (int q = 0; q < IGRP; ++q)
        out[po + (size_t)q * N] = vals[q][r];
    }
  }
}

extern "C" void kernel_launch(void* const* d_in, const int* in_sizes, int n_in,
                              void* d_out, int out_size, void* d_ws, size_t ws_size,
                              hipStream_t stream) {
  const float* xyz = (const float*)d_in[0];
  const float* W1  = (const float*)d_in[1];
  const float* b1  = (const float*)d_in[2];
  const float* W2  = (const float*)d_in[3];
  const float* b2  = (const float*)d_in[4];
  float* out = (float*)d_out;

  const long long in0 = in_sizes[0];
  const int N = (int)((3LL * (long long)out_size) / (8LL * in0));
  const int B = (int)(in0 / (3LL * N));

  dim3 grid(N / JT, N / IT, B);
  relposenc_occ<<<grid, WAVES * 64, 0, stream>>>(xyz, W1, b1, W2, b2, out, N);
}

// Round 11
// 25.454 us; speedup vs baseline: 2.1754x; 2.1754x over previous
//
#include <hip/hip_runtime.h>

#define HID   64
#define NHD   8
#define IT    8           // i's per block -> 1024 blocks = 4/CU, 32 waves/CU
#define IGRP  4           // i's per store burst
#define WAVES 8
#define JTW   32          // j's per wave (2 MFMA tiles of 16)
#define JT    (WAVES*JTW) // 256 j's per block

typedef _Float16 f16x8 __attribute__((ext_vector_type(8)));
typedef float    f32x4 __attribute__((ext_vector_type(4)));

// out[b,k,i,j] = sum_h relu( (u_j[h]+b1[h]) - u_i[h] ) * W2[h,k] + b2[k]
// r5/r9 fp16 MFMA pipeline (validated). r10 lesson: (512,8) bounds forced
// VGPR 56->32 and spilled to scratch (FETCH 58GB, WRITE 3x) — keep (512,4)
// which gave VGPR=56/no spills, and take occupancy from the grid only:
// IT 16->8 doubles blocks to 1024 (4/CU), doubling resident waves vs r9.
__global__ __launch_bounds__(WAVES * 64, 4) void relposenc_occ2(
    const float* __restrict__ xyz, const float* __restrict__ W1,
    const float* __restrict__ b1,  const float* __restrict__ W2,
    const float* __restrict__ b2,  float* __restrict__ out, int N) {

  __shared__ float    sW1b1[4][HID];
  __shared__ _Float16 sU[IT][HID];

  const int tid  = threadIdx.x;
  const int wave = tid >> 6;
  const int lane = tid & 63;
  const int col  = lane & 15;
  const int hgrp = lane >> 4;
  const int b    = blockIdx.z;
  const int i0   = blockIdx.y * IT;
  const int j0   = blockIdx.x * JT + wave * JTW;

  const float* xb = xyz + (size_t)b * 3 * N;

  if (tid < 4 * HID) {
    int r = tid >> 6, h = tid & 63;
    sW1b1[r][h] = (r < 3) ? W1[r * HID + h] : b1[h];
  }
  if (tid < IT * HID) {
    int ii = tid >> 6, h = tid & 63;
    int i  = i0 + ii;
    float u = fmaf(xb[i], W1[h],
              fmaf(xb[N + i], W1[HID + h],
                   xb[2 * N + i] * W1[2 * HID + h]));
    sU[ii][h] = (_Float16)u;
  }

  f16x8 aLo[2], aHi[2];
  #pragma unroll
  for (int kb = 0; kb < 2; ++kb)
    #pragma unroll
    for (int e = 0; e < 8; ++e) {
      int h = kb * 32 + hgrp * 8 + e;
      aLo[kb][e] = (_Float16)((col < NHD)  ? W2[h * NHD + col]       : 0.f);
      aHi[kb][e] = (_Float16)((col >= NHD) ? W2[h * NHD + (col - 8)] : 0.f);
    }
  float b2v[4];
  #pragma unroll
  for (int r = 0; r < 4; ++r) b2v[r] = b2[((hgrp & 1) << 2) + r];

  __syncthreads();

  f16x8 aj[2][2];
  #pragma unroll
  for (int t = 0; t < 2; ++t) {
    int j = j0 + t * 16 + col;
    float x0 = xb[j], x1 = xb[N + j], x2 = xb[2 * N + j];
    #pragma unroll
    for (int kb = 0; kb < 2; ++kb)
      #pragma unroll
      for (int e = 0; e < 8; ++e) {
        int h = kb * 32 + hgrp * 8 + e;
        float v = fmaf(x0, sW1b1[0][h],
                  fmaf(x1, sW1b1[1][h],
                  fmaf(x2, sW1b1[2][h], sW1b1[3][h])));
        aj[t][kb][e] = (_Float16)v;
      }
  }

  const size_t jj = (size_t)j0 + col + ((size_t)(lane >> 5) << 4);
  const int kbase = (hgrp & 1) << 2;
  const size_t baseOff = ((size_t)(b * NHD + kbase) * N + i0) * N + jj;
  const size_t plane = (size_t)N * N;

  const f16x8 z = {0, 0, 0, 0, 0, 0, 0, 0};

  for (int ig = 0; ig < IT; ig += IGRP) {
    f32x4 vals[IGRP];

    #pragma unroll
    for (int q = 0; q < IGRP; ++q) {
      f16x8 u0 = *(const f16x8*)&sU[ig + q][hgrp * 8];
      f16x8 u1 = *(const f16x8*)&sU[ig + q][32 + hgrp * 8];

      f16x8 d00 = __builtin_elementwise_max(aj[0][0] - u0, z);
      f16x8 d01 = __builtin_elementwise_max(aj[0][1] - u1, z);
      f16x8 d10 = __builtin_elementwise_max(aj[1][0] - u0, z);
      f16x8 d11 = __builtin_elementwise_max(aj[1][1] - u1, z);

      f32x4 cA = {b2v[0], b2v[1], b2v[2], b2v[3]};
      f32x4 cB = {0.f, 0.f, 0.f, 0.f};
      cA = __builtin_amdgcn_mfma_f32_16x16x32_f16(aLo[0], d00, cA, 0, 0, 0);
      cA = __builtin_amdgcn_mfma_f32_16x16x32_f16(aLo[1], d01, cA, 0, 0, 0);
      cB = __builtin_amdgcn_mfma_f32_16x16x32_f16(aHi[0], d10, cB, 0, 0, 0);
      cB = __builtin_amdgcn_mfma_f32_16x16x32_f16(aHi[1], d11, cB, 0, 0, 0);
      vals[q] = cA + cB;
    }

    #pragma unroll
    for (int r = 0; r < 4; ++r) {
      const size_t po = baseOff + (size_t)r * plane + (size_t)ig * N;
      #pragma unroll
      for (int q = 0; q < IGRP; ++q)
        out[po + (size_t)q * N] = vals[q][r];
    }
  }
}

extern "C" void kernel_launch(void* const* d_in, const int* in_sizes, int n_in,
                              void* d_out, int out_size, void* d_ws, size_t ws_size,
                              hipStream_t stream) {
  const float* xyz = (const float*)d_in[0];
  const float* W1  = (const float*)d_in[1];
  const float* b1  = (const float*)d_in[2];
  const float* W2  = (const float*)d_in[3];
  const float* b2  = (const float*)d_in[4];
  float* out = (float*)d_out;

  const long long in0 = in_sizes[0];
  const int N = (int)((3LL * (long long)out_size) / (8LL * in0));
  const int B = (int)(in0 / (3LL * N));

  dim3 grid(N / JT, N / IT, B);
  relposenc_occ2<<<grid, WAVES * 64, 0, stream>>>(xyz, W1, b1, W2, b2, out, N);
}

// Round 12
// 22.762 us; speedup vs baseline: 2.4326x; 1.1183x over previous
//
#include <hip/hip_runtime.h>

#define HID   64
#define NHD   8
#define IT    16          // i's per block -> 512 blocks = 2/CU
#define IGRP  4           // i's per store burst
#define WAVES 8
#define JTW   32          // j's per wave (2 MFMA tiles of 16)
#define JT    (WAVES*JTW) // 256 j's per block

typedef _Float16 f16x8 __attribute__((ext_vector_type(8)));
typedef float    f32x4 __attribute__((ext_vector_type(4)));

// out[b,k,i,j] = sum_h relu( (u_j[h]+b1[h]) - u_i[h] ) * W2[h,k] + b2[k]
// r9 pipeline (validated, 23.9us). This round: the fitted model across r2-r11
// is dur ~= F*(blocks/CU) + bytes/BW with F ~6-8us of PROLOGUE latency — the
// afrag build's 32 per-lane W2 gathers serialize at ~400cy each (VGPR=56
// can't pipeline them). Fix: stage W2 via ONE coalesced load into padded LDS
// ([64][9] to spread fragment-read banks) and b2 into LDS; build fragments
// from LDS after the barrier. Store phase unchanged.
__global__ __launch_bounds__(WAVES * 64, 4) void relposenc_pro(
    const float* __restrict__ xyz, const float* __restrict__ W1,
    const float* __restrict__ b1,  const float* __restrict__ W2,
    const float* __restrict__ b2,  float* __restrict__ out, int N) {

  __shared__ float    sW1b1[4][HID];
  __shared__ float    sW2p[HID][NHD + 1];   // +1 pad: spread banks on frag read
  __shared__ float    sB2[NHD];
  __shared__ _Float16 sU[IT][HID];

  const int tid  = threadIdx.x;
  const int wave = tid >> 6;
  const int lane = tid & 63;
  const int col  = lane & 15;
  const int hgrp = lane >> 4;
  const int b    = blockIdx.z;
  const int i0   = blockIdx.y * IT;
  const int j0   = blockIdx.x * JT + wave * JTW;

  const float* xb = xyz + (size_t)b * 3 * N;

  // ---- coalesced staging: W2 (512 floats, one per thread) ----
  sW2p[tid >> 3][tid & 7] = W2[tid];
  // ---- W1/b1 ----
  if (tid < 4 * HID) {
    int r = tid >> 6, h = tid & 63;
    sW1b1[r][h] = (r < 3) ? W1[r * HID + h] : b1[h];
  }
  if (tid < NHD) sB2[tid] = b2[tid];
  // ---- u_i for the block's 16 i's (coalesced W1 reads, uniform xb reads) ----
  for (int t = tid; t < IT * HID; t += WAVES * 64) {
    int ii = t >> 6, h = t & 63;
    int i  = i0 + ii;
    float u = fmaf(xb[i], W1[h],
              fmaf(xb[N + i], W1[HID + h],
                   xb[2 * N + i] * W1[2 * HID + h]));
    sU[ii][h] = (_Float16)u;
  }

  __syncthreads();

  // ---- A fragments from LDS (was: 32 serialized global gathers) ----
  f16x8 aLo[2], aHi[2];
  #pragma unroll
  for (int kb = 0; kb < 2; ++kb)
    #pragma unroll
    for (int e = 0; e < 8; ++e) {
      int h = kb * 32 + hgrp * 8 + e;
      aLo[kb][e] = (_Float16)((col < NHD)  ? sW2p[h][col]     : 0.f);
      aHi[kb][e] = (_Float16)((col >= NHD) ? sW2p[h][col - 8] : 0.f);
    }
  const int kbase = (hgrp & 1) << 2;
  float b2v[4];
  #pragma unroll
  for (int r = 0; r < 4; ++r) b2v[r] = sB2[kbase + r];

  // ---- aj = u_j + b1 (f16) for this lane's 2 j's ----
  f16x8 aj[2][2];
  #pragma unroll
  for (int t = 0; t < 2; ++t) {
    int j = j0 + t * 16 + col;
    float x0 = xb[j], x1 = xb[N + j], x2 = xb[2 * N + j];
    #pragma unroll
    for (int kb = 0; kb < 2; ++kb)
      #pragma unroll
      for (int e = 0; e < 8; ++e) {
        int h = kb * 32 + hgrp * 8 + e;
        float v = fmaf(x0, sW1b1[0][h],
                  fmaf(x1, sW1b1[1][h],
                  fmaf(x2, sW1b1[2][h], sW1b1[3][h])));
        aj[t][kb][e] = (_Float16)v;
      }
  }

  const size_t jj = (size_t)j0 + col + ((size_t)(lane >> 5) << 4);
  const size_t baseOff = ((size_t)(b * NHD + kbase) * N + i0) * N + jj;
  const size_t plane = (size_t)N * N;

  const f16x8 z = {0, 0, 0, 0, 0, 0, 0, 0};

  for (int ig = 0; ig < IT; ig += IGRP) {
    f32x4 vals[IGRP];

    #pragma unroll
    for (int q = 0; q < IGRP; ++q) {
      f16x8 u0 = *(const f16x8*)&sU[ig + q][hgrp * 8];
      f16x8 u1 = *(const f16x8*)&sU[ig + q][32 + hgrp * 8];

      f16x8 d00 = __builtin_elementwise_max(aj[0][0] - u0, z);
      f16x8 d01 = __builtin_elementwise_max(aj[0][1] - u1, z);
      f16x8 d10 = __builtin_elementwise_max(aj[1][0] - u0, z);
      f16x8 d11 = __builtin_elementwise_max(aj[1][1] - u1, z);

      f32x4 cA = {b2v[0], b2v[1], b2v[2], b2v[3]};
      f32x4 cB = {0.f, 0.f, 0.f, 0.f};
      cA = __builtin_amdgcn_mfma_f32_16x16x32_f16(aLo[0], d00, cA, 0, 0, 0);
      cA = __builtin_amdgcn_mfma_f32_16x16x32_f16(aLo[1], d01, cA, 0, 0, 0);
      cB = __builtin_amdgcn_mfma_f32_16x16x32_f16(aHi[0], d10, cB, 0, 0, 0);
      cB = __builtin_amdgcn_mfma_f32_16x16x32_f16(aHi[1], d11, cB, 0, 0, 0);
      vals[q] = cA + cB;
    }

    #pragma unroll
    for (int r = 0; r < 4; ++r) {
      const size_t po = baseOff + (size_t)r * plane + (size_t)ig * N;
      #pragma unroll
      for (int q = 0; q < IGRP; ++q)
        out[po + (size_t)q * N] = vals[q][r];
    }
  }
}

extern "C" void kernel_launch(void* const* d_in, const int* in_sizes, int n_in,
                              void* d_out, int out_size, void* d_ws, size_t ws_size,
                              hipStream_t stream) {
  const float* xyz = (const float*)d_in[0];
  const float* W1  = (const float*)d_in[1];
  const float* b1  = (const float*)d_in[2];
  const float* W2  = (const float*)d_in[3];
  const float* b2  = (const float*)d_in[4];
  float* out = (float*)d_out;

  const long long in0 = in_sizes[0];
  const int N = (int)((3LL * (long long)out_size) / (8LL * in0));
  const int B = (int)(in0 / (3LL * N));

  dim3 grid(N / JT, N / IT, B);
  relposenc_pro<<<grid, WAVES * 64, 0, stream>>>(xyz, W1, b1, W2, b2, out, N);
}